// Round 1
// baseline (401.502 us; speedup 1.0000x reference)
//
#include <hip/hip_runtime.h>

#define TN_ (128*512)
#define TE_ (128*2048)
#define B_ 128
#define NPG 512
#define NREL 114

// monotone float->uint key (total order matching float compare, no NaNs here)
__device__ __forceinline__ unsigned fkey(float f){
  unsigned u = __float_as_uint(f);
  return (u & 0x80000000u) ? ~u : (u | 0x80000000u);
}
__device__ __forceinline__ float fdec(unsigned k){
  return (k & 0x80000000u) ? __uint_as_float(k & 0x7FFFFFFFu) : __uint_as_float(~k);
}

__global__ void k_init(const float* __restrict__ emb, const int* __restrict__ xattr,
                       float* __restrict__ x, int* __restrict__ mask){
  int i = blockIdx.x*blockDim.x + threadIdx.x;
  if (i >= TN_) return;
  int a = xattr[i];
  #pragma unroll
  for (int d=0; d<16; d++) x[i*16+d] = emb[a*16+d];
  mask[i] = 1;
}

// Wq[r][d] = sum_o W[r][d][o]*q[o];  Wk likewise
__global__ void k_wqk(const float* __restrict__ W, const float* __restrict__ q,
                      const float* __restrict__ k, float* __restrict__ wq,
                      float* __restrict__ wk){
  int t = blockIdx.x*blockDim.x + threadIdx.x; // t = r*16 + d
  if (t >= NREL*16) return;
  const float* wrow = W + t*16;
  float aq=0.f, ak=0.f;
  #pragma unroll
  for (int o=0;o<16;o++){ aq += wrow[o]*q[o]; ak += wrow[o]*k[o]; }
  wq[t]=aq; wk[t]=ak;
}

__global__ void k_edge_logit(const int* __restrict__ src, const int* __restrict__ dst,
                             const int* __restrict__ et, const float* __restrict__ x,
                             const int* __restrict__ mask, const float* __restrict__ wq,
                             const float* __restrict__ wk, float* __restrict__ logit,
                             unsigned* __restrict__ mkey){
  __shared__ float swq[NREL*16];
  __shared__ float swk[NREL*16];
  for (int i=threadIdx.x; i<NREL*16; i+=blockDim.x){ swq[i]=wq[i]; swk[i]=wk[i]; }
  __syncthreads();
  int e = blockIdx.x*blockDim.x + threadIdx.x;
  if (e >= TE_) return;
  int s=src[e], t=dst[e];
  if (!mask[s] || !mask[t]) return;
  int r = et[e];
  const float* xs = x + s*16;
  const float* xt = x + t*16;
  const float* Q = swq + r*16;
  const float* K = swk + r*16;
  float acc=0.f;
  #pragma unroll
  for(int d=0;d<16;d++) acc += xt[d]*Q[d] + xs[d]*K[d];
  float lg = acc > 0.f ? acc : 0.2f*acc;   // leaky_relu 0.2
  logit[e]=lg;
  atomicMax(mkey + t, fkey(lg));
}

// thread = e*16 + o: h_s[o] = sum_d x_s[d]*W[r][d][o]; accumulate num/den
__global__ void k_edge_acc(const int* __restrict__ src, const int* __restrict__ dst,
                           const int* __restrict__ et, const float* __restrict__ x,
                           const int* __restrict__ mask, const float* __restrict__ W,
                           const float* __restrict__ logit, const unsigned* __restrict__ mkey,
                           float* __restrict__ num, float* __restrict__ den){
  int tid = blockIdx.x*blockDim.x + threadIdx.x;
  int e = tid>>4, o = tid&15;
  if (e >= TE_) return;
  int s=src[e], t=dst[e];
  if (!mask[s] || !mask[t]) return;
  float m = fdec(mkey[t]);
  float ex = expf(logit[e]-m);
  const float* xs = x + s*16;
  const float* wr = W + et[e]*256 + o;
  float h=0.f;
  #pragma unroll
  for(int d=0;d<16;d++) h += xs[d]*wr[d*16];
  atomicAdd(num + t*16 + o, ex*h);
  if (o==0) atomicAdd(den + t, ex);
}

// one block per graph: normalize+relu, mean/max pool, (optional) top-k pooling
__global__ void k_node(const float* __restrict__ num, const float* __restrict__ den,
                       const float* __restrict__ bvec, const float* __restrict__ pw,
                       float* __restrict__ x, int* __restrict__ mask,
                       float* __restrict__ feats, int l, int cnt, int kk, int do_pool){
  __shared__ float s_sum[16];
  __shared__ unsigned s_max[16];
  __shared__ unsigned s_keys[NPG];
  __shared__ int s_cnt;
  __shared__ int s_w[8];
  int b = blockIdx.x, tid = threadIdx.x;
  int i = b*NPG + tid;
  int alive = mask[i];
  float v[16];
  if (alive){
    float dn = den[i];
    float inv = dn>0.f ? 1.f/dn : 1.f;   // ref: where(den>0, den, 1)
    #pragma unroll
    for(int o=0;o<16;o++){ float z = num[i*16+o]*inv + bvec[o]; v[o] = z>0.f?z:0.f; }
  } else {
    #pragma unroll
    for(int o=0;o<16;o++) v[o]=0.f;
  }
  if (tid<16){ s_sum[tid]=0.f; s_max[tid]=0u; }
  __syncthreads();
  #pragma unroll
  for(int o=0;o<16;o++){
    atomicAdd(&s_sum[o], v[o]);
    if (alive) atomicMax(&s_max[o], __float_as_uint(v[o])); // relu'd => >=0, uint order ok
  }
  __syncthreads();
  if (tid<16){
    feats[b*96 + l*32 + tid]      = s_sum[tid]/(float)cnt;
    feats[b*96 + l*32 + 16 + tid] = __uint_as_float(s_max[tid]);
  }
  if (!do_pool) return;

  // score = tanh((v . pw)/||pw||)
  float sc;
  {
    float ss=0.f, dot=0.f;
    #pragma unroll
    for(int o=0;o<16;o++){ float p = pw[o]; ss += p*p; dot += v[o]*p; }
    sc = tanhf(dot / sqrtf(ss));
  }
  s_keys[tid] = alive ? fkey(sc) : 0u;   // masked -> smallest
  __syncthreads();

  // bitwise binary search: largest K with count(keys >= K) >= kk
  unsigned cur = 0u;
  for (int bit=31; bit>=0; --bit){
    unsigned cand = cur | (1u<<bit);
    if (tid==0) s_cnt = 0;
    __syncthreads();
    int p = (s_keys[tid] >= cand) ? 1 : 0;
    #pragma unroll
    for (int off=32; off; off>>=1) p += __shfl_down(p, off, 64);
    if ((tid&63)==0) atomicAdd(&s_cnt, p);
    __syncthreads();
    int c = s_cnt;
    __syncthreads();
    if (c >= kk) cur = cand;
  }
  // count strictly greater
  if (tid==0) s_cnt = 0;
  __syncthreads();
  {
    int p = (s_keys[tid] > cur) ? 1 : 0;
    #pragma unroll
    for (int off=32; off; off>>=1) p += __shfl_down(p, off, 64);
    if ((tid&63)==0) atomicAdd(&s_cnt, p);
  }
  __syncthreads();
  int cgt = s_cnt;
  __syncthreads();
  int ties = kk - cgt;

  // rank among equals by node index (matches jax top_k lowest-index tie-break)
  bool eq = alive && (s_keys[tid] == cur);
  unsigned long long bal = __ballot(eq);
  int lane = tid & 63, wv = tid >> 6;
  int lrank = __popcll(bal & ((1ull<<lane)-1ull));
  if (lane==0) s_w[wv] = __popcll(bal);
  __syncthreads();
  int pre=0;
  #pragma unroll
  for (int w=0; w<8; ++w) if (w<wv) pre += s_w[w];
  int rank = pre + lrank;

  bool keep = alive && ((s_keys[tid] > cur) || (eq && rank < ties));
  float mult = keep ? sc : 0.f;
  #pragma unroll
  for(int o=0;o<16;o++) x[i*16+o] = v[o]*mult;
  mask[i] = keep ? 1 : 0;
}

__global__ void k_mlp(const float* __restrict__ feats, const float* __restrict__ w1,
                      const float* __restrict__ b1, const float* __restrict__ w2,
                      const float* __restrict__ b2, const float* __restrict__ w3,
                      const float* __restrict__ b3, float* __restrict__ out){
  int b = blockIdx.x*blockDim.x + threadIdx.x;
  if (b >= B_) return;
  const float* g = feats + b*96;
  float h1[16];
  #pragma unroll
  for(int j=0;j<16;j++){
    float a = b1[j];
    for(int i=0;i<96;i++) a += g[i]*w1[i*16+j];
    h1[j] = a>0.f?a:0.f;
  }
  float h2[4];
  #pragma unroll
  for(int j=0;j<4;j++){
    float a = b2[j];
    #pragma unroll
    for(int i=0;i<16;i++) a += h1[i]*w2[i*4+j];
    h2[j]=a>0.f?a:0.f;
  }
  float z = b3[0];
  #pragma unroll
  for(int i=0;i<4;i++) z += h2[i]*w3[i];
  out[b] = 1.f/(1.f+expf(-z));
}

extern "C" void kernel_launch(void* const* d_in, const int* in_sizes, int n_in,
                              void* d_out, int out_size, void* d_ws, size_t ws_size,
                              hipStream_t stream) {
  const float* emb    = (const float*)d_in[0];
  const float* gnn_w  = (const float*)d_in[1];
  const float* gnn_q  = (const float*)d_in[2];
  const float* gnn_k  = (const float*)d_in[3];
  const float* gnn_b  = (const float*)d_in[4];
  const float* pool_w = (const float*)d_in[5];
  const float* w1 = (const float*)d_in[6];
  const float* b1 = (const float*)d_in[7];
  const float* w2 = (const float*)d_in[8];
  const float* b2 = (const float*)d_in[9];
  const float* w3 = (const float*)d_in[10];
  const float* b3 = (const float*)d_in[11];
  const int* xattr = (const int*)d_in[12];
  const int* eidx  = (const int*)d_in[13];
  const int* etype = (const int*)d_in[14];
  const int* src = eidx;
  const int* dst = eidx + TE_;

  char* ws = (char*)d_ws;
  float* x      = (float*)ws; ws += (size_t)TN_*16*4;
  int*   mask   = (int*)ws;   ws += (size_t)TN_*4;
  float* logit  = (float*)ws; ws += (size_t)TE_*4;
  // contiguous zero region (one memset): mkey, den, num
  unsigned* mkey= (unsigned*)ws; ws += (size_t)TN_*4;
  float* den    = (float*)ws; ws += (size_t)TN_*4;
  float* num    = (float*)ws; ws += (size_t)TN_*16*4;
  float* feats  = (float*)ws; ws += (size_t)B_*96*4;
  float* wq     = (float*)ws; ws += (size_t)NREL*16*4;
  float* wk     = (float*)ws; ws += (size_t)NREL*16*4;

  k_init<<<TN_/256, 256, 0, stream>>>(emb, xattr, x, mask);

  const int cnts[3] = {512, 410, 328};   // static alive counts
  const int kks[3]  = {410, 328, 0};     // ceil(0.8*512), ceil(0.8*410)

  for (int l=0; l<3; ++l){
    hipMemsetAsync(mkey, 0, ((size_t)TN_ + TN_ + (size_t)TN_*16)*4, stream);
    k_wqk<<<(NREL*16+255)/256, 256, 0, stream>>>(gnn_w + (size_t)l*NREL*256,
                                                 gnn_q + l*16, gnn_k + l*16, wq, wk);
    k_edge_logit<<<TE_/256, 256, 0, stream>>>(src, dst, etype, x, mask, wq, wk, logit, mkey);
    k_edge_acc<<<(TE_*16)/256, 256, 0, stream>>>(src, dst, etype, x, mask,
                                                 gnn_w + (size_t)l*NREL*256, logit, mkey, num, den);
    k_node<<<B_, NPG, 0, stream>>>(num, den, gnn_b + l*16, pool_w + (l<2? l:1)*16,
                                   x, mask, feats, l, cnts[l], kks[l], (l<2)?1:0);
  }
  k_mlp<<<1, 128, 0, stream>>>(feats, w1, b1, w2, b2, w3, b3, (float*)d_out);
}

// Round 2
// 233.204 us; speedup vs baseline: 1.7217x; 1.7217x over previous
//
#include <hip/hip_runtime.h>

#define TN_ (128*512)
#define TE_ (128*2048)
#define B_ 128
#define NPG 512
#define NREL 114

// monotone float->uint key (total order matching float compare, no NaNs here)
__device__ __forceinline__ unsigned fkey(float f){
  unsigned u = __float_as_uint(f);
  return (u & 0x80000000u) ? ~u : (u | 0x80000000u);
}
__device__ __forceinline__ float fdec(unsigned k){
  return (k & 0x80000000u) ? __uint_as_float(k & 0x7FFFFFFFu) : __uint_as_float(~k);
}

__global__ void k_init(const float* __restrict__ emb, const int* __restrict__ xattr,
                       float* __restrict__ x, int* __restrict__ mask){
  int i = blockIdx.x*blockDim.x + threadIdx.x;
  if (i >= TN_) return;
  int a = xattr[i];
  const float4* e4 = (const float4*)(emb + a*16);
  float4* x4 = (float4*)(x + (size_t)i*16);
  #pragma unroll
  for (int q=0; q<4; q++) x4[q] = e4[q];
  mask[i] = 1;
}

// all layers at once: wq[l][r][d] = sum_o W[l][r][d][o]*q[l][o]
__global__ void k_wqk(const float* __restrict__ W, const float* __restrict__ q,
                      const float* __restrict__ k, float* __restrict__ wq,
                      float* __restrict__ wk){
  int t = blockIdx.x*blockDim.x + threadIdx.x; // t = l*1824 + r*16 + d
  if (t >= 3*NREL*16) return;
  int l = t / (NREL*16);
  const float* wrow = W + (size_t)t*16;
  const float* qv = q + l*16;
  const float* kv = k + l*16;
  float aq=0.f, ak=0.f;
  #pragma unroll
  for (int o=0;o<16;o++){ aq += wrow[o]*qv[o]; ak += wrow[o]*kv[o]; }
  wq[t]=aq; wk[t]=ak;
}

__global__ void k_edge_logit(const int* __restrict__ src, const int* __restrict__ dst,
                             const int* __restrict__ et, const float* __restrict__ x,
                             const int* __restrict__ mask, const float* __restrict__ wq,
                             const float* __restrict__ wk, float* __restrict__ logit,
                             unsigned* __restrict__ mkey){
  __shared__ float swq[NREL*16];
  __shared__ float swk[NREL*16];
  for (int i=threadIdx.x; i<NREL*16; i+=blockDim.x){ swq[i]=wq[i]; swk[i]=wk[i]; }
  __syncthreads();
  int e = blockIdx.x*blockDim.x + threadIdx.x;
  if (e >= TE_) return;
  int s=src[e], t=dst[e];
  if (!mask[s] || !mask[t]) return;
  int r = et[e];
  const float* xs = x + (size_t)s*16;
  const float* xt = x + (size_t)t*16;
  const float* Q = swq + r*16;
  const float* K = swk + r*16;
  float acc=0.f;
  #pragma unroll
  for(int d=0;d<16;d++) acc += xt[d]*Q[d] + xs[d]*K[d];
  float lg = acc > 0.f ? acc : 0.2f*acc;   // leaky_relu 0.2
  logit[e]=lg;
  atomicMax(mkey + t, fkey(lg));
}

// thread = e*16 + o: h_s[o] = sum_d x_s[d]*W[r][d][o]; accumulate num/den
__global__ void k_edge_acc(const int* __restrict__ src, const int* __restrict__ dst,
                           const int* __restrict__ et, const float* __restrict__ x,
                           const int* __restrict__ mask, const float* __restrict__ W,
                           const float* __restrict__ logit, const unsigned* __restrict__ mkey,
                           float* __restrict__ num, float* __restrict__ den){
  int tid = blockIdx.x*blockDim.x + threadIdx.x;
  int e = tid>>4, o = tid&15;
  if (e >= TE_) return;
  int s=src[e], t=dst[e];
  if (!mask[s] || !mask[t]) return;
  float m = fdec(mkey[t]);
  float ex = expf(logit[e]-m);
  const float* xs = x + (size_t)s*16;
  const float* wr = W + (size_t)et[e]*256 + o;
  float h=0.f;
  #pragma unroll
  for(int d=0;d<16;d++) h += xs[d]*wr[d*16];
  atomicAdd(num + (size_t)t*16 + o, ex*h);
  if (o==0) atomicAdd(den + t, ex);
}

// one block per graph: normalize+relu, mean/max pool, (optional) top-k pooling
// search is wave-redundant & register-resident: zero __syncthreads in the bit loop
__global__ void k_node(const float* __restrict__ num, const float* __restrict__ den,
                       const float* __restrict__ bvec, const float* __restrict__ pw,
                       float* __restrict__ x, int* __restrict__ mask,
                       float* __restrict__ feats, int l, int cnt, int kk, int do_pool){
  __shared__ float s_sum[16];
  __shared__ unsigned s_max[16];
  __shared__ unsigned s_keys[NPG];
  __shared__ int s_w[8];
  int b = blockIdx.x, tid = threadIdx.x;
  int lane = tid & 63, wv = tid >> 6;
  int i = b*NPG + tid;
  int alive = mask[i];
  float v[16];
  if (alive){
    float dn = den[i];
    float inv = dn>0.f ? 1.f/dn : 1.f;   // ref: where(den>0, den, 1)
    const float4* n4 = (const float4*)(num + (size_t)i*16);
    #pragma unroll
    for(int q=0;q<4;q++){
      float4 t = n4[q];
      float z0 = t.x*inv + bvec[4*q+0]; v[4*q+0] = z0>0.f?z0:0.f;
      float z1 = t.y*inv + bvec[4*q+1]; v[4*q+1] = z1>0.f?z1:0.f;
      float z2 = t.z*inv + bvec[4*q+2]; v[4*q+2] = z2>0.f?z2:0.f;
      float z3 = t.w*inv + bvec[4*q+3]; v[4*q+3] = z3>0.f?z3:0.f;
    }
  } else {
    #pragma unroll
    for(int o=0;o<16;o++) v[o]=0.f;
  }
  if (tid<16){ s_sum[tid]=0.f; s_max[tid]=0u; }
  __syncthreads();
  // wave-level reduce, then one shared atomic per wave per component
  #pragma unroll
  for(int o=0;o<16;o++){
    float s = v[o], m = v[o];
    #pragma unroll
    for (int off=32; off; off>>=1){
      s += __shfl_xor(s, off);
      m = fmaxf(m, __shfl_xor(m, off));
    }
    if (lane==0){ atomicAdd(&s_sum[o], s); atomicMax(&s_max[o], __float_as_uint(m)); }
  }
  __syncthreads();
  if (tid<16){
    feats[b*96 + l*32 + tid]      = s_sum[tid]/(float)cnt;
    feats[b*96 + l*32 + 16 + tid] = __uint_as_float(s_max[tid]);
  }
  if (!do_pool) return;

  // score = tanh((v . pw)/||pw||)
  float sc;
  {
    float ss=0.f, dot=0.f;
    #pragma unroll
    for(int o=0;o<16;o++){ float p = pw[o]; ss += p*p; dot += v[o]*p; }
    sc = tanhf(dot / sqrtf(ss));
  }
  unsigned mykey = alive ? fkey(sc) : 0u;   // masked -> smallest (real keys never 0)
  s_keys[tid] = mykey;
  __syncthreads();

  // each wave pulls all 512 keys into registers once; search is register-only
  unsigned kreg[8];
  #pragma unroll
  for (int j=0;j<8;j++) kreg[j] = s_keys[lane + j*64];

  // bitwise binary search: largest K with count(keys >= K) >= kk
  unsigned cur = 0u;
  for (int bit=31; bit>=0; --bit){
    unsigned cand = cur | (1u<<bit);
    int c = 0;
    #pragma unroll
    for (int j=0;j<8;j++) c += (kreg[j] >= cand) ? 1 : 0;
    #pragma unroll
    for (int off=32; off; off>>=1) c += __shfl_xor(c, off);
    if (c >= kk) cur = cand;
  }
  int cgt = 0;
  #pragma unroll
  for (int j=0;j<8;j++) cgt += (kreg[j] > cur) ? 1 : 0;
  #pragma unroll
  for (int off=32; off; off>>=1) cgt += __shfl_xor(cgt, off);
  int ties = kk - cgt;

  // rank among equals by node index (matches jax top_k lowest-index tie-break)
  bool eq = alive && (mykey == cur);
  unsigned long long bal = __ballot(eq);
  int lrank = __popcll(bal & ((1ull<<lane)-1ull));
  if (lane==0) s_w[wv] = __popcll(bal);
  __syncthreads();
  int pre=0;
  #pragma unroll
  for (int w=0; w<8; ++w) if (w<wv) pre += s_w[w];
  int rank = pre + lrank;

  bool keep = alive && ((mykey > cur) || (eq && rank < ties));
  float mult = keep ? sc : 0.f;
  float4* x4 = (float4*)(x + (size_t)i*16);
  #pragma unroll
  for(int q=0;q<4;q++){
    float4 t; t.x=v[4*q+0]*mult; t.y=v[4*q+1]*mult; t.z=v[4*q+2]*mult; t.w=v[4*q+3]*mult;
    x4[q] = t;
  }
  mask[i] = keep ? 1 : 0;
}

__global__ void k_mlp(const float* __restrict__ feats, const float* __restrict__ w1,
                      const float* __restrict__ b1, const float* __restrict__ w2,
                      const float* __restrict__ b2, const float* __restrict__ w3,
                      const float* __restrict__ b3, float* __restrict__ out){
  int b = blockIdx.x*blockDim.x + threadIdx.x;
  if (b >= B_) return;
  const float* g = feats + b*96;
  float h1[16];
  #pragma unroll
  for(int j=0;j<16;j++){
    float a = b1[j];
    for(int i=0;i<96;i++) a += g[i]*w1[i*16+j];
    h1[j] = a>0.f?a:0.f;
  }
  float h2[4];
  #pragma unroll
  for(int j=0;j<4;j++){
    float a = b2[j];
    #pragma unroll
    for(int i=0;i<16;i++) a += h1[i]*w2[i*4+j];
    h2[j]=a>0.f?a:0.f;
  }
  float z = b3[0];
  #pragma unroll
  for(int i=0;i<4;i++) z += h2[i]*w3[i];
  out[b] = 1.f/(1.f+expf(-z));
}

extern "C" void kernel_launch(void* const* d_in, const int* in_sizes, int n_in,
                              void* d_out, int out_size, void* d_ws, size_t ws_size,
                              hipStream_t stream) {
  const float* emb    = (const float*)d_in[0];
  const float* gnn_w  = (const float*)d_in[1];
  const float* gnn_q  = (const float*)d_in[2];
  const float* gnn_k  = (const float*)d_in[3];
  const float* gnn_b  = (const float*)d_in[4];
  const float* pool_w = (const float*)d_in[5];
  const float* w1 = (const float*)d_in[6];
  const float* b1 = (const float*)d_in[7];
  const float* w2 = (const float*)d_in[8];
  const float* b2 = (const float*)d_in[9];
  const float* w3 = (const float*)d_in[10];
  const float* b3 = (const float*)d_in[11];
  const int* xattr = (const int*)d_in[12];
  const int* eidx  = (const int*)d_in[13];
  const int* etype = (const int*)d_in[14];
  const int* src = eidx;
  const int* dst = eidx + TE_;

  char* ws = (char*)d_ws;
  float* x      = (float*)ws; ws += (size_t)TN_*16*4;
  int*   mask   = (int*)ws;   ws += (size_t)TN_*4;
  float* logit  = (float*)ws; ws += (size_t)TE_*4;
  // contiguous zero region (one memset): mkey, den, num
  unsigned* mkey= (unsigned*)ws; ws += (size_t)TN_*4;
  float* den    = (float*)ws; ws += (size_t)TN_*4;
  float* num    = (float*)ws; ws += (size_t)TN_*16*4;
  float* feats  = (float*)ws; ws += (size_t)B_*96*4;
  float* wq     = (float*)ws; ws += (size_t)3*NREL*16*4;
  float* wk     = (float*)ws; ws += (size_t)3*NREL*16*4;

  k_init<<<TN_/256, 256, 0, stream>>>(emb, xattr, x, mask);
  k_wqk<<<(3*NREL*16+255)/256, 256, 0, stream>>>(gnn_w, gnn_q, gnn_k, wq, wk);

  const int cnts[3] = {512, 410, 328};   // static alive counts
  const int kks[3]  = {410, 328, 0};     // ceil(0.8*512), ceil(0.8*410)

  for (int l=0; l<3; ++l){
    hipMemsetAsync(mkey, 0, ((size_t)TN_ + TN_ + (size_t)TN_*16)*4, stream);
    k_edge_logit<<<TE_/256, 256, 0, stream>>>(src, dst, etype, x, mask,
                                              wq + (size_t)l*NREL*16, wk + (size_t)l*NREL*16,
                                              logit, mkey);
    k_edge_acc<<<(TE_*16)/256, 256, 0, stream>>>(src, dst, etype, x, mask,
                                                 gnn_w + (size_t)l*NREL*256, logit, mkey, num, den);
    k_node<<<B_, NPG, 0, stream>>>(num, den, gnn_b + l*16, pool_w + (l<2? l:1)*16,
                                   x, mask, feats, l, cnts[l], kks[l], (l<2)?1:0);
  }
  k_mlp<<<1, 128, 0, stream>>>(feats, w1, b1, w2, b2, w3, b3, (float*)d_out);
}

// Round 3
// 186.291 us; speedup vs baseline: 2.1552x; 1.2518x over previous
//
#include <hip/hip_runtime.h>

#define B_ 128
#define NPG 512
#define EPG 2048
#define NREL 114

// monotone float->uint key (total order matching float compare, no NaNs here)
__device__ __forceinline__ unsigned fkey(float f){
  unsigned u = __float_as_uint(f);
  return (u & 0x80000000u) ? ~u : (u | 0x80000000u);
}
__device__ __forceinline__ float fdec(unsigned k){
  return (k & 0x80000000u) ? __uint_as_float(k & 0x7FFFFFFFu) : __uint_as_float(~k);
}

// One block per graph. Whole network (emb gather -> 3 RGAT layers with
// top-k pooling -> pooled feats -> MLP head) LDS-resident, 1 launch total.
__global__ __launch_bounds__(1024) void k_fused(
    const float* __restrict__ emb, const float* __restrict__ gnn_w,
    const float* __restrict__ gnn_q, const float* __restrict__ gnn_k,
    const float* __restrict__ gnn_b, const float* __restrict__ pool_w,
    const float* __restrict__ w1, const float* __restrict__ b1,
    const float* __restrict__ w2, const float* __restrict__ b2,
    const float* __restrict__ w3, const float* __restrict__ b3,
    const int* __restrict__ xattr, const int* __restrict__ src,
    const int* __restrict__ dst, const int* __restrict__ et,
    float* __restrict__ out)
{
  // stride-17 pads: without them x/num/wq hit 16..32-way bank conflicts
  __shared__ float s_x[NPG*17];
  __shared__ float s_num[NPG*17];
  __shared__ float s_wq[NREL*17];
  __shared__ float s_wk[NREL*17];
  __shared__ float s_logit[EPG];
  __shared__ unsigned s_mkey[NPG];
  __shared__ float s_den[NPG];
  __shared__ int s_mask[NPG];
  __shared__ unsigned short s_src[EPG], s_dst[EPG], s_et[EPG];
  __shared__ unsigned s_keys[NPG];
  __shared__ float s_sum[16];
  __shared__ unsigned s_max16[16];
  __shared__ int s_w[8];
  __shared__ float s_feats[96];
  __shared__ float s_h1[16], s_h2[4];

  const int b = blockIdx.x, tid = threadIdx.x;
  const int lane = tid & 63, wv = tid >> 6;

  // ---- init: node features (emb gather) + edge lists (once, reused 3 layers)
  if (tid < NPG){
    int a = xattr[b*NPG + tid];
    #pragma unroll
    for (int d=0; d<16; d++) s_x[tid*17+d] = emb[a*16+d];
    s_mask[tid] = 1;
  }
  for (int e = tid; e < EPG; e += 1024){
    s_src[e] = (unsigned short)(src[(size_t)b*EPG+e] - b*NPG);
    s_dst[e] = (unsigned short)(dst[(size_t)b*EPG+e] - b*NPG);
    s_et[e]  = (unsigned short)et[(size_t)b*EPG+e];
  }

  const int cnts[3] = {512, 410, 328};   // static alive counts
  const int kks[3]  = {410, 328, 0};     // ceil(0.8*512), ceil(0.8*410)

  for (int l=0; l<3; ++l){
    // ---- A: per-layer Wq/Wk precompute (logit is bilinear) + zero accumulators
    {
      const float* Wl = gnn_w + (size_t)l*NREL*256;
      const float* qv = gnn_q + l*16;
      const float* kv = gnn_k + l*16;
      for (int i = tid; i < NREL*16; i += 1024){
        const float* wrow = Wl + (size_t)i*16;
        float aq=0.f, ak=0.f;
        #pragma unroll
        for (int o=0;o<16;o++){ aq += wrow[o]*qv[o]; ak += wrow[o]*kv[o]; }
        s_wq[(i>>4)*17 + (i&15)] = aq;
        s_wk[(i>>4)*17 + (i&15)] = ak;
      }
      for (int i = tid; i < NPG*17; i += 1024) s_num[i] = 0.f;
      if (tid < NPG){ s_mkey[tid]=0u; s_den[tid]=0.f; }
    }
    __syncthreads();
    // ---- P1: edge logits + segment max (LDS atomicMax on monotone key)
    for (int e = tid; e < EPG; e += 1024){
      int s = s_src[e], t = s_dst[e];
      if (!s_mask[s] || !s_mask[t]) continue;
      int r17 = (int)s_et[e]*17;
      float acc = 0.f;
      #pragma unroll
      for (int d=0; d<16; d++)
        acc += s_x[t*17+d]*s_wq[r17+d] + s_x[s*17+d]*s_wk[r17+d];
      float lg = acc > 0.f ? acc : 0.2f*acc;   // leaky_relu 0.2
      s_logit[e] = lg;
      atomicMax(&s_mkey[t], fkey(lg));
    }
    __syncthreads();
    // ---- P2: h_s = x_s * W_r and weighted aggregation; 4 lanes per edge,
    //      lane og owns outputs [4og..4og+3]; W rows read as coalesced float4
    {
      const float* Wl = gnn_w + (size_t)l*NREL*256;
      const int og = tid & 3;
      for (int e = (tid>>2); e < EPG; e += 256){
        int s = s_src[e], t = s_dst[e];
        if (!s_mask[s] || !s_mask[t]) continue;
        float m = fdec(s_mkey[t]);
        float ex = expf(s_logit[e] - m);
        const float4* wr = (const float4*)(Wl + (size_t)s_et[e]*256) + og;
        float h0=0.f,h1=0.f,h2=0.f,h3=0.f;
        #pragma unroll 4
        for (int d=0; d<16; d++){
          float xs = s_x[s*17+d];
          float4 w = wr[d*4];
          h0 += xs*w.x; h1 += xs*w.y; h2 += xs*w.z; h3 += xs*w.w;
        }
        int base = t*17 + og*4;
        atomicAdd(&s_num[base+0], ex*h0);
        atomicAdd(&s_num[base+1], ex*h1);
        atomicAdd(&s_num[base+2], ex*h2);
        atomicAdd(&s_num[base+3], ex*h3);
        if (og==0) atomicAdd(&s_den[t], ex);
      }
    }
    __syncthreads();
    if (tid < 16){ s_sum[tid]=0.f; s_max16[tid]=0u; }
    __syncthreads();
    // ---- N: normalize + relu + mean/max pool (dead nodes are 0, relu>=0 so
    //      including them in max is safe; mean divides by static cnt)
    float v[16]; float sc = 0.f; unsigned mykey = 0u; int alive = 0;
    if (tid < NPG){
      alive = s_mask[tid];
      if (alive){
        float dn = s_den[tid];
        float inv = dn>0.f ? 1.f/dn : 1.f;   // ref: where(den>0, den, 1)
        #pragma unroll
        for (int o=0;o<16;o++){
          float z = s_num[tid*17+o]*inv + gnn_b[l*16+o];
          v[o] = z>0.f?z:0.f;
        }
      } else {
        #pragma unroll
        for (int o=0;o<16;o++) v[o]=0.f;
      }
      #pragma unroll
      for (int o=0;o<16;o++){
        float sv=v[o], mv=v[o];
        #pragma unroll
        for (int off=32; off; off>>=1){
          sv += __shfl_xor(sv, off);
          mv = fmaxf(mv, __shfl_xor(mv, off));
        }
        if (lane==0){ atomicAdd(&s_sum[o], sv); atomicMax(&s_max16[o], __float_as_uint(mv)); }
      }
    }
    __syncthreads();
    if (tid < 16){
      s_feats[l*32 + tid]      = s_sum[tid]/(float)cnts[l];
      s_feats[l*32 + 16 + tid] = __uint_as_float(s_max16[tid]);
    }
    if (l < 2){
      const int kk = kks[l];
      if (tid < NPG){
        float ss=0.f, dot=0.f;
        #pragma unroll
        for (int o=0;o<16;o++){ float p = pool_w[l*16+o]; ss += p*p; dot += v[o]*p; }
        sc = tanhf(dot / sqrtf(ss));
        mykey = alive ? fkey(sc) : 0u;   // dead -> 0; alive keys always > 0
        s_keys[tid] = mykey;
      }
      __syncthreads();
      // register-resident wave-redundant bitwise search for the kk-th key
      int ties=0, lrank=0; bool eq=false; unsigned cur=0u;
      if (tid < NPG){
        unsigned kreg[8];
        #pragma unroll
        for (int j=0;j<8;j++) kreg[j] = s_keys[lane + j*64];
        for (int bit=31; bit>=0; --bit){
          unsigned cand = cur | (1u<<bit);
          int c=0;
          #pragma unroll
          for (int j=0;j<8;j++) c += (kreg[j] >= cand) ? 1 : 0;
          #pragma unroll
          for (int off=32; off; off>>=1) c += __shfl_xor(c, off);
          if (c >= kk) cur = cand;
        }
        int cgt=0;
        #pragma unroll
        for (int j=0;j<8;j++) cgt += (kreg[j] > cur) ? 1 : 0;
        #pragma unroll
        for (int off=32; off; off>>=1) cgt += __shfl_xor(cgt, off);
        ties = kk - cgt;
        // rank among equals by node index (jax top_k lowest-index tie-break)
        eq = alive && (mykey == cur);
        unsigned long long bal = __ballot(eq);
        lrank = __popcll(bal & ((1ull<<lane)-1ull));
        if (lane==0) s_w[wv] = __popcll(bal);
      }
      __syncthreads();
      if (tid < NPG){
        int pre=0;
        #pragma unroll
        for (int w=0; w<8; ++w) if (w<wv) pre += s_w[w];
        int rank = pre + lrank;
        bool keep = alive && ((mykey > cur) || (eq && rank < ties));
        float mult = keep ? sc : 0.f;
        #pragma unroll
        for (int o=0;o<16;o++) s_x[tid*17+o] = v[o]*mult;
        s_mask[tid] = keep ? 1 : 0;
      }
      __syncthreads();
    } else {
      __syncthreads();   // make s_feats visible for the MLP
    }
  }

  // ---- MLP head (per graph, feats never leave LDS)
  if (tid < 16){
    float a = b1[tid];
    for (int i=0;i<96;i++) a += s_feats[i]*w1[i*16+tid];
    s_h1[tid] = a>0.f?a:0.f;
  }
  __syncthreads();
  if (tid < 4){
    float a = b2[tid];
    #pragma unroll
    for (int i=0;i<16;i++) a += s_h1[i]*w2[i*4+tid];
    s_h2[tid] = a>0.f?a:0.f;
  }
  __syncthreads();
  if (tid == 0){
    float z = b3[0];
    #pragma unroll
    for (int i=0;i<4;i++) z += s_h2[i]*w3[i];
    out[b] = 1.f/(1.f+expf(-z));
  }
}

extern "C" void kernel_launch(void* const* d_in, const int* in_sizes, int n_in,
                              void* d_out, int out_size, void* d_ws, size_t ws_size,
                              hipStream_t stream) {
  const float* emb    = (const float*)d_in[0];
  const float* gnn_w  = (const float*)d_in[1];
  const float* gnn_q  = (const float*)d_in[2];
  const float* gnn_k  = (const float*)d_in[3];
  const float* gnn_b  = (const float*)d_in[4];
  const float* pool_w = (const float*)d_in[5];
  const float* w1 = (const float*)d_in[6];
  const float* b1 = (const float*)d_in[7];
  const float* w2 = (const float*)d_in[8];
  const float* b2 = (const float*)d_in[9];
  const float* w3 = (const float*)d_in[10];
  const float* b3 = (const float*)d_in[11];
  const int* xattr = (const int*)d_in[12];
  const int* eidx  = (const int*)d_in[13];
  const int* etype = (const int*)d_in[14];
  const int* src = eidx;
  const int* dst = eidx + (size_t)B_*EPG;

  k_fused<<<B_, 1024, 0, stream>>>(emb, gnn_w, gnn_q, gnn_k, gnn_b, pool_w,
                                   w1, b1, w2, b2, w3, b3,
                                   xattr, src, dst, etype, (float*)d_out);
}